// Round 9
// baseline (141.915 us; speedup 1.0000x reference)
//
#include <hip/hip_runtime.h>

#define BATCH   262144
#define IN_DIM  28
#define HID     128
#define LAT     64
#define NCODES  512
#define NBLK    256             // 1024 rows per block (16 waves x 64 rows)
#define WVS     16
#define NWAVE   (NBLK * WVS)    // 4096

// ---- quad-grouped LDS table geometry ----
// Element (row,k) stored at row*S + q'*(K/4) + j*4 + e where k = j*16 + q'*4 + e.
// A lane (lm, quad) reads K/4 CONTIGUOUS shorts at row*S + quad*(K/4): pure
// ds_read_b128, 16B-aligned. Strides 40/72/136 shorts give 2-way bank aliasing
// only (free). Each v8s read covers TWO logical-k chunks, feeding ONE
// mfma_16x16x32 (k-relabeling valid: both operands share the slot ordering).
#define S1 40     // lw1  [128][40]  K=32  (k>=28 zero)
#define S2 136    // lw2/ld2 [..][136] K=128
#define SC 72     // lcb/ld1 [..][72]  K=64
#define O_LW1 0
#define O_LW2 5120
#define O_LCB 13824
#define O_LD1 50688
#define O_LD2 59904
#define BLOB_SHORTS 64256
#define BLOB_F32    864
#define BLOB_BYTES  (BLOB_SHORTS * 2 + BLOB_F32 * 4)   // 131968
#define LDS_BYTES   BLOB_BYTES

// prep thread-index regions (e2 is 8-lane-parallel)
#define E2_BASE   BLOB_SHORTS            // 4096 threads (8 per code)
#define B1_BASE   (BLOB_SHORTS + 4096)
#define B2_BASE   (B1_BASE + 128)
#define DB1_BASE  (B2_BASE + 64)
#define DB2_BASE  (DB1_BASE + 128)
#define PREP_END  (DB2_BASE + 32)

typedef short v4s __attribute__((ext_vector_type(4)));
typedef short v8s __attribute__((ext_vector_type(8)));
typedef float v4f __attribute__((ext_vector_type(4)));

union u4v8 { unsigned u[4]; v8s s; };

__device__ __forceinline__ unsigned short f2bf(float f) {   // RNE (prep only)
  unsigned u = __float_as_uint(f);
  u += 0x7fffu + ((u >> 16) & 1u);
  return (unsigned short)(u >> 16);
}
// pack two truncated bf16 (hi, lo) in ONE v_perm_b32 (truncation validated r7/r8)
__device__ __forceinline__ unsigned pk(float hi, float lo) {
  return __builtin_amdgcn_perm(__float_as_uint(hi), __float_as_uint(lo), 0x07060302u);
}
// unpack truncated-bf16 lanes of a pk'd u32 back to f32 (for the loss diff)
__device__ __forceinline__ float xf0(unsigned u) { return __uint_as_float(u << 16); }
__device__ __forceinline__ float xf1(unsigned u) { return __uint_as_float(u & 0xFFFF0000u); }

// 16x16x32 bf16 MFMA. C-layout row = quad*4+r (shape-determined),
// so chained stages keep working; the v8s B-operand is two pk'd register pairs.
__device__ __forceinline__ v4f mfma32(v8s a, v8s b, v4f c) {
  return __builtin_amdgcn_mfma_f32_16x16x32_bf16(a, b, c, 0, 0, 0);
}

__device__ __forceinline__ v8s rlpk2(v4f h0, v4f h1) {   // relu+pack 2 C-tiles
  u4v8 c;
  c.u[0] = pk(fmaxf(h0[1], 0.f), fmaxf(h0[0], 0.f));
  c.u[1] = pk(fmaxf(h0[3], 0.f), fmaxf(h0[2], 0.f));
  c.u[2] = pk(fmaxf(h1[1], 0.f), fmaxf(h1[0], 0.f));
  c.u[3] = pk(fmaxf(h1[3], 0.f), fmaxf(h1[2], 0.f));
  return c.s;
}
__device__ __forceinline__ v8s zpk2(v4f z0, v4f z1) {    // pack 2 C-tiles
  u4v8 c;
  c.u[0] = pk(z0[1], z0[0]); c.u[1] = pk(z0[3], z0[2]);
  c.u[2] = pk(z1[1], z1[0]); c.u[3] = pk(z1[3], z1[2]);
  return c.s;
}
__device__ __forceinline__ v8s mkv8(unsigned a, unsigned b, unsigned c2, unsigned d) {
  u4v8 c; c.u[0] = a; c.u[1] = b; c.u[2] = c2; c.u[3] = d; return c.s;
}
// argmin key: dist upper bits | 9-bit code (float order == dist order to 2^-14 rel;
// lowest code wins ties among equal upper bits)
__device__ __forceinline__ float kpack(float d, unsigned code) {
  return __uint_as_float((__float_as_uint(d) & 0xFFFFFE00u) | code);
}

// Blob layout (short offsets), quad-grouped, pad zeroed:
//   lw1 @0      [128 hid][40]   enc_w1^T   (K=32 slot, k>=28 zero)
//   lw2 @5120   [64  lat][136]  enc_w2^T   (K=128)
//   lcb @13824  [512 code][72]  bf16(-2*codebook) (K=64)
//   ld1 @50688  [128 hid][72]   bf16(-0.5*dec_w1^T)  (scale cancels -2q)
//   ld2 @59904  [32  n][136]    dec_w2^T   (rows n>=28 zero)
// f32 @ byte 128512: e2[512], b1[128], b2[64], db1[128], db2[32 pad0]
__global__ __launch_bounds__(256) void vq_prep(
    const float* __restrict__ ew1, const float* __restrict__ eb1,
    const float* __restrict__ ew2, const float* __restrict__ eb2,
    const float* __restrict__ cb,  const float* __restrict__ dw1,
    const float* __restrict__ db1, const float* __restrict__ dw2,
    const float* __restrict__ db2,
    unsigned short* __restrict__ blob) {
  int i = blockIdx.x * 256 + threadIdx.x;
  float* fb = (float*)(blob + BLOB_SHORTS);
  if (i < O_LW2) {                       // lw1 [128][40] K=32 per=8
    int row = i / S1, s = i % S1;
    unsigned short v = 0;
    if (s < 32) {
      int q = s >> 3, r2 = s & 7, j = r2 >> 2, e = r2 & 3;
      int k = j * 16 + q * 4 + e;
      if (k < IN_DIM) v = f2bf(ew1[k * HID + row]);
    }
    blob[i] = v;
  } else if (i < O_LCB) {                // lw2 [64][136] K=128 per=32
    int j2 = i - O_LW2; int row = j2 / S2, s = j2 % S2;
    unsigned short v = 0;
    if (s < 128) {
      int q = s >> 5, r2 = s & 31, j = r2 >> 2, e = r2 & 3;
      int k = j * 16 + q * 4 + e;
      v = f2bf(ew2[k * LAT + row]);
    }
    blob[i] = v;
  } else if (i < O_LD1) {                // lcb [512][72] K=64 per=16, = -2*cb
    int j2 = i - O_LCB; int row = j2 / SC, s = j2 % SC;
    unsigned short v = 0;
    if (s < 64) {
      int q = s >> 4, r2 = s & 15, j = r2 >> 2, e = r2 & 3;
      int k = j * 16 + q * 4 + e;
      v = f2bf(-2.0f * cb[row * LAT + k]);
    }
    blob[i] = v;
  } else if (i < O_LD2) {                // ld1 [128][72] = -0.5*dec_w1^T
    int j2 = i - O_LD1; int row = j2 / SC, s = j2 % SC;
    unsigned short v = 0;
    if (s < 64) {
      int q = s >> 4, r2 = s & 15, j = r2 >> 2, e = r2 & 3;
      int k = j * 16 + q * 4 + e;
      v = f2bf(-0.5f * dw1[k * HID + row]);
    }
    blob[i] = v;
  } else if (i < BLOB_SHORTS) {          // ld2 [32][136]
    int j2 = i - O_LD2; int row = j2 / S2, s = j2 % S2;
    unsigned short v = 0;
    if (s < 128 && row < IN_DIM) {
      int q = s >> 5, r2 = s & 31, j = r2 >> 2, e = r2 & 3;
      int k = j * 16 + q * 4 + e;
      v = f2bf(dw2[k * IN_DIM + row]);
    }
    blob[i] = v;
  } else if (i < B1_BASE) {              // e2: 8 lanes per code, float4 loads
    int j = i - E2_BASE;                 // wave-aligned region
    int c = j >> 3, l = j & 7;
    const float* p = cb + c * LAT + l * 8;
    float4 a = *(const float4*)p;
    float4 b = *(const float4*)(p + 4);
    float s = a.x * a.x + a.y * a.y + a.z * a.z + a.w * a.w
            + b.x * b.x + b.y * b.y + b.z * b.z + b.w * b.w;
    s += __shfl_xor(s, 1, 64);
    s += __shfl_xor(s, 2, 64);
    s += __shfl_xor(s, 4, 64);
    if (l == 0) fb[c] = s;
  } else if (i < B2_BASE) {
    fb[512 + (i - B1_BASE)] = eb1[i - B1_BASE];
  } else if (i < DB1_BASE) {
    fb[640 + (i - B2_BASE)] = eb2[i - B2_BASE];
  } else if (i < DB2_BASE) {
    fb[704 + (i - DB1_BASE)] = db1[i - DB1_BASE];
  } else if (i < PREP_END) {
    int k = i - DB2_BASE;
    fb[832 + k] = (k < IN_DIM) ? db2[k] : 0.f;
  }
}

// ---- 2-tile stage 1+2 (mfma32): unchanged from r17 (proven spill-free) ----
__device__ __forceinline__ void s12_pair(
    const unsigned short* __restrict__ L, const float* __restrict__ LF,
    int lm, int quad, v8s bxa, v8s bxb,
    v8s& zfa01, v8s& zfa23, v8s& zfb01, v8s& zfb23,
    float& z2a, float& z2b) {
  const int fw1 = O_LW1 + lm * S1 + quad * 8;
  const int fw2 = O_LW2 + lm * S2 + quad * 32;
  v4f za[4], zb[4];
#pragma unroll
  for (int nt = 0; nt < 4; ++nt) {
    v4f s = *(const v4f*)&LF[640 + nt * 16 + quad * 4];      // b2 seed (broadcast)
    za[nt] = s; zb[nt] = s;
  }
#pragma unroll 1
  for (int jp = 0; jp < 4; ++jp) {
    v8s hA, hB;
    {
      v8s w0 = *(const v8s*)&L[fw1 + (2 * jp) * (16 * S1)];
      v4f s0 = *(const v4f*)&LF[512 + (2 * jp) * 16 + quad * 4];     // b1 seed
      v8s w1 = *(const v8s*)&L[fw1 + (2 * jp + 1) * (16 * S1)];
      v4f s1 = *(const v4f*)&LF[512 + (2 * jp + 1) * 16 + quad * 4];
      v4f h0a = mfma32(w0, bxa, s0);
      v4f h1a = mfma32(w1, bxa, s1);
      v4f h0b = mfma32(w0, bxb, s0);
      v4f h1b = mfma32(w1, bxb, s1);
      hA = rlpk2(h0a, h1a);
      hB = rlpk2(h0b, h1b);
    }
#pragma unroll
    for (int nt = 0; nt < 4; ++nt) {
      v8s w2 = *(const v8s*)&L[fw2 + nt * (16 * S2) + jp * 8];
      za[nt] = mfma32(w2, hA, za[nt]);
      zb[nt] = mfma32(w2, hB, zb[nt]);
    }
  }
  z2a = za[0][0] * za[0][0] + za[0][1] * za[0][1] + za[0][2] * za[0][2] + za[0][3] * za[0][3]
      + za[1][0] * za[1][0] + za[1][1] * za[1][1] + za[1][2] * za[1][2] + za[1][3] * za[1][3]
      + za[2][0] * za[2][0] + za[2][1] * za[2][1] + za[2][2] * za[2][2] + za[2][3] * za[2][3]
      + za[3][0] * za[3][0] + za[3][1] * za[3][1] + za[3][2] * za[3][2] + za[3][3] * za[3][3];
  z2b = zb[0][0] * zb[0][0] + zb[0][1] * zb[0][1] + zb[0][2] * zb[0][2] + zb[0][3] * zb[0][3]
      + zb[1][0] * zb[1][0] + zb[1][1] * zb[1][1] + zb[1][2] * zb[1][2] + zb[1][3] * zb[1][3]
      + zb[2][0] * zb[2][0] + zb[2][1] * zb[2][1] + zb[2][2] * zb[2][2] + zb[2][3] * zb[2][3]
      + zb[3][0] * zb[3][0] + zb[3][1] * zb[3][1] + zb[3][2] * zb[3][2] + zb[3][3] * zb[3][3];
  zfa01 = zpk2(za[0], za[1]); zfa23 = zpk2(za[2], za[3]);
  zfb01 = zpk2(zb[0], zb[1]); zfb23 = zpk2(zb[2], zb[3]);
}

// ---- 2-tile stage 5+6 (mfma32): unchanged from r17 ----
__device__ __forceinline__ void s56_pair(
    const unsigned short* __restrict__ L, const float* __restrict__ LF,
    int lm, int quad, int codeA, int codeB,
    unsigned xa0, unsigned xa1, unsigned xa2, unsigned xa3,
    unsigned xb0, unsigned xb1, unsigned xb2, unsigned xb3,
    float* __restrict__ orowA, float* __restrict__ orowB, float& racc) {
  const int fd1 = O_LD1 + lm * SC + quad * 16;
  const int fd2 = O_LD2 + lm * S2 + quad * 32;
  const int gA = O_LCB + codeA * SC + quad * 16;   // -2q rows (wave-uniform code)
  const int gB = O_LCB + codeB * SC + quad * 16;
  v8s qa0 = *(const v8s*)&L[gA];
  v8s qa1 = *(const v8s*)&L[gA + 8];
  v8s qb0 = *(const v8s*)&L[gB];
  v8s qb1 = *(const v8s*)&L[gB + 8];
  v4f a6a[2], a6b[2];
#pragma unroll
  for (int nt = 0; nt < 2; ++nt) {
    v4f s = *(const v4f*)&LF[832 + nt * 16 + quad * 4];      // db2 seed
    a6a[nt] = s; a6b[nt] = s;
  }
#pragma unroll 1
  for (int jp = 0; jp < 4; ++jp) {
    v8s hA, hB;
    {
      int j0 = 2 * jp;
      v8s d00 = *(const v8s*)&L[fd1 + j0 * (16 * SC)];
      v8s d01 = *(const v8s*)&L[fd1 + j0 * (16 * SC) + 8];
      v4f s0 = *(const v4f*)&LF[704 + j0 * 16 + quad * 4];   // db1 seed
      v8s d10 = *(const v8s*)&L[fd1 + (j0 + 1) * (16 * SC)];
      v8s d11 = *(const v8s*)&L[fd1 + (j0 + 1) * (16 * SC) + 8];
      v4f s1 = *(const v4f*)&LF[704 + (j0 + 1) * 16 + quad * 4];
      v4f h0 = mfma32(d00, qa0, s0);
      h0 = mfma32(d01, qa1, h0);
      v4f h1 = mfma32(d10, qa0, s1);
      h1 = mfma32(d11, qa1, h1);
      hA = rlpk2(h0, h1);
      h0 = mfma32(d00, qb0, s0);
      h0 = mfma32(d01, qb1, h0);
      h1 = mfma32(d10, qb0, s1);
      h1 = mfma32(d11, qb1, h1);
      hB = rlpk2(h0, h1);
    }
#pragma unroll
    for (int nt = 0; nt < 2; ++nt) {
      v8s w6 = *(const v8s*)&L[fd2 + nt * (16 * S2) + jp * 8];
      a6a[nt] = mfma32(w6, hA, a6a[nt]);
      a6b[nt] = mfma32(w6, hB, a6b[nt]);
    }
  }
  *(float4*)(orowA + quad * 4) = (float4){a6a[0][0], a6a[0][1], a6a[0][2], a6a[0][3]};
  *(float4*)(orowB + quad * 4) = (float4){a6b[0][0], a6b[0][1], a6b[0][2], a6b[0][3]};
  if (quad < 3) {
    *(float4*)(orowA + 16 + quad * 4) = (float4){a6a[1][0], a6a[1][1], a6a[1][2], a6a[1][3]};
    *(float4*)(orowB + 16 + quad * 4) = (float4){a6b[1][0], a6b[1][1], a6b[1][2], a6b[1][3]};
  }
  float d;
  d = a6a[0][0] - xf0(xa0); racc += d * d;
  d = a6a[0][1] - xf1(xa0); racc += d * d;
  d = a6a[0][2] - xf0(xa1); racc += d * d;
  d = a6a[0][3] - xf1(xa1); racc += d * d;
  d = a6a[1][0] - xf0(xa2); racc += d * d;   // quad3: a6[1]==0 and x==0
  d = a6a[1][1] - xf1(xa2); racc += d * d;
  d = a6a[1][2] - xf0(xa3); racc += d * d;
  d = a6a[1][3] - xf1(xa3); racc += d * d;
  d = a6b[0][0] - xf0(xb0); racc += d * d;
  d = a6b[0][1] - xf1(xb0); racc += d * d;
  d = a6b[0][2] - xf0(xb1); racc += d * d;
  d = a6b[0][3] - xf1(xb1); racc += d * d;
  d = a6b[1][0] - xf0(xb2); racc += d * d;
  d = a6b[1][1] - xf1(xb2); racc += d * d;
  d = a6b[1][2] - xf0(xb3); racc += d * d;
  d = a6b[1][3] - xf1(xb3); racc += d * d;
}

// ---------------- fused main kernel ----------------
// Round-18: 4-tile-shared argmin. r17's pipe accounting: LDS 43% (argmin = 55%
// of reads), MFMA 34%, VALU 14% -- latency-bound with LDS the largest pipe.
// The wave's 64 rows now flow as S12(A,B) -> S12(C,D) -> ONE argmin over all 4
// tiles (each cb fragment pair feeds 8 MFMA instead of 4) -> S56(A,B) ->
// S56(C,D). LDS reads per 64 rows: 232 -> 168 (-28%). Register peak at argmin
// ~96 of the 128/wave budget (4 waves/EU); FETCH/WRITE are the spill tripwire.
// C,D x-loads issue before S12(A,B) so HBM latency hides under compute.
__global__ __attribute__((amdgpu_flat_work_group_size(1024, 1024)))
__attribute__((amdgpu_waves_per_eu(4, 4)))
void vq_main(
    const float* __restrict__ x,
    const unsigned short* __restrict__ blob,
    float* __restrict__ out, float* __restrict__ partials) {

  extern __shared__ __align__(16) char smem[];
  const unsigned short* L = (const unsigned short*)smem;
  const float*         LF = (const float*)(smem + BLOB_SHORTS * 2);

  const int tid  = threadIdx.x;
  const int wave = tid >> 6;
  const int lane = tid & 63;
  const int quad = lane >> 4;
  const int lm   = lane & 15;

  // ---- stage tables into LDS (one-time) ----
  {
    const float4* src = (const float4*)blob;
    float4* dst = (float4*)smem;
#pragma unroll
    for (int it = 0; it < 9; ++it) {
      int idx = it * 1024 + tid;
      if (idx < BLOB_BYTES / 16) dst[idx] = src[idx];
    }
  }
  __syncthreads();

  const int rbase = blockIdx.x * 1024 + wave * 64;
  float racc = 0.f, vqacc = 0.f;

  // ---- x load -> packed bf16 for all 4 tiles (loads issue up front) ----
  unsigned xa0, xa1, xa2, xa3, xb0, xb1, xb2, xb3;
  unsigned xc0, xc1, xc2, xc3, xd0, xd1, xd2, xd3;
  {
    const float* xpa = x + (size_t)(rbase + lm) * IN_DIM;
    const float* xpb = x + (size_t)(rbase + 16 + lm) * IN_DIM;
    const float* xpc = x + (size_t)(rbase + 32 + lm) * IN_DIM;
    const float* xpd = x + (size_t)(rbase + 48 + lm) * IN_DIM;
    float4 t = *(const float4*)(xpa + quad * 4);
    xa0 = pk(t.y, t.x); xa1 = pk(t.w, t.z);
    t = (quad < 3) ? *(const float4*)(xpa + 16 + quad * 4) : (float4){0.f, 0.f, 0.f, 0.f};
    xa2 = pk(t.y, t.x); xa3 = pk(t.w, t.z);
    t = *(const float4*)(xpb + quad * 4);
    xb0 = pk(t.y, t.x); xb1 = pk(t.w, t.z);
    t = (quad < 3) ? *(const float4*)(xpb + 16 + quad * 4) : (float4){0.f, 0.f, 0.f, 0.f};
    xb2 = pk(t.y, t.x); xb3 = pk(t.w, t.z);
    t = *(const float4*)(xpc + quad * 4);
    xc0 = pk(t.y, t.x); xc1 = pk(t.w, t.z);
    t = (quad < 3) ? *(const float4*)(xpc + 16 + quad * 4) : (float4){0.f, 0.f, 0.f, 0.f};
    xc2 = pk(t.y, t.x); xc3 = pk(t.w, t.z);
    t = *(const float4*)(xpd + quad * 4);
    xd0 = pk(t.y, t.x); xd1 = pk(t.w, t.z);
    t = (quad < 3) ? *(const float4*)(xpd + 16 + quad * 4) : (float4){0.f, 0.f, 0.f, 0.f};
    xd2 = pk(t.y, t.x); xd3 = pk(t.w, t.z);
  }

  // ---- stages 1+2: pairs (A,B) then (C,D) ----
  v8s zfa01, zfa23, zfb01, zfb23, zfc01, zfc23, zfd01, zfd23;
  float z2a, z2b, z2c, z2d;
  s12_pair(L, LF, lm, quad,
           mkv8(xa0, xa1, xa2, xa3), mkv8(xb0, xb1, xb2, xb3),
           zfa01, zfa23, zfb01, zfb23, z2a, z2b);
  __builtin_amdgcn_sched_barrier(0);
  s12_pair(L, LF, lm, quad,
           mkv8(xc0, xc1, xc2, xc3), mkv8(xd0, xd1, xd2, xd3),
           zfc01, zfc23, zfd01, zfd23, z2c, z2d);
  __builtin_amdgcn_sched_barrier(0);

  // ---- 4-tile argmin: each cb fragment pair feeds all 4 tiles ----
  const int fcb = O_LCB + lm * SC + quad * 16;
  float bkA = __uint_as_float(0x7f7fffffu);
  float bkB = bkA, bkC = bkA, bkD = bkA;
#pragma unroll 2
  for (int ct = 0; ct < 32; ++ct) {
    v8s c0 = *(const v8s*)&L[fcb + ct * (16 * SC)];        // k-chunks 0,1
    v8s c1 = *(const v8s*)&L[fcb + ct * (16 * SC) + 8];    // k-chunks 2,3
    v4f sd = *(const v4f*)&LF[ct * 16 + quad * 4];         // e2 seed
    v4f dA = mfma32(c0, zfa01, sd);
    dA = mfma32(c1, zfa23, dA);
    v4f dB = mfma32(c0, zfb01, sd);
    dB = mfma32(c1, zfb23, dB);
    v4f dC = mfma32(c0, zfc01, sd);
    dC = mfma32(c1, zfc23, dC);
    v4f dD = mfma32(c0, zfd01, sd);
    dD = mfma32(c1, zfd23, dD);
    unsigned cbase = (unsigned)(ct * 16 + quad * 4);
    bkA = fminf(bkA, fminf(fminf(kpack(dA[0], cbase), kpack(dA[1], cbase + 1)),
                           fminf(kpack(dA[2], cbase + 2), kpack(dA[3], cbase + 3))));
    bkB = fminf(bkB, fminf(fminf(kpack(dB[0], cbase), kpack(dB[1], cbase + 1)),
                           fminf(kpack(dB[2], cbase + 2), kpack(dB[3], cbase + 3))));
    bkC = fminf(bkC, fminf(fminf(kpack(dC[0], cbase), kpack(dC[1], cbase + 1)),
                           fminf(kpack(dC[2], cbase + 2), kpack(dC[3], cbase + 3))));
    bkD = fminf(bkD, fminf(fminf(kpack(dD[0], cbase), kpack(dD[1], cbase + 1)),
                           fminf(kpack(dD[2], cbase + 2), kpack(dD[3], cbase + 3))));
  }

  // ---- cross-quad argmin + z2 reduce (all 4 tiles) ----
#pragma unroll
  for (int off = 16; off < 64; off <<= 1) {
    bkA = fminf(bkA, __shfl_xor(bkA, off, 64));
    bkB = fminf(bkB, __shfl_xor(bkB, off, 64));
    bkC = fminf(bkC, __shfl_xor(bkC, off, 64));
    bkD = fminf(bkD, __shfl_xor(bkD, off, 64));
    z2a += __shfl_xor(z2a, off, 64);
    z2b += __shfl_xor(z2b, off, 64);
    z2c += __shfl_xor(z2c, off, 64);
    z2d += __shfl_xor(z2d, off, 64);
  }
  unsigned ka = __float_as_uint(bkA), kb = __float_as_uint(bkB);
  unsigned kc = __float_as_uint(bkC), kd = __float_as_uint(bkD);
  int codeA = (int)(ka & 511u), codeB = (int)(kb & 511u);
  int codeC = (int)(kc & 511u), codeD = (int)(kd & 511u);
  if (quad == 0)
    vqacc += z2a + __uint_as_float(ka & 0xFFFFFE00u)
           + z2b + __uint_as_float(kb & 0xFFFFFE00u)
           + z2c + __uint_as_float(kc & 0xFFFFFE00u)
           + z2d + __uint_as_float(kd & 0xFFFFFE00u);      // ||z-q||^2
  __builtin_amdgcn_sched_barrier(0);

  // ---- stages 5+6 + store + loss: pairs (A,B) then (C,D) ----
  s56_pair(L, LF, lm, quad, codeA, codeB,
           xa0, xa1, xa2, xa3, xb0, xb1, xb2, xb3,
           out + (size_t)(rbase + lm) * IN_DIM,
           out + (size_t)(rbase + 16 + lm) * IN_DIM, racc);
  __builtin_amdgcn_sched_barrier(0);
  s56_pair(L, LF, lm, quad, codeC, codeD,
           xc0, xc1, xc2, xc3, xd0, xd1, xd2, xd3,
           out + (size_t)(rbase + 32 + lm) * IN_DIM,
           out + (size_t)(rbase + 48 + lm) * IN_DIM, racc);

  // ---- per-wave butterfly, per-wave partial store (no atomics) ----
#pragma unroll
  for (int off = 1; off < 64; off <<= 1) {
    racc  += __shfl_xor(racc, off, 64);
    vqacc += __shfl_xor(vqacc, off, 64);
  }
  if (lane == 0) {
    size_t w = (size_t)blockIdx.x * WVS + wave;
    partials[w * 2]     = racc;
    partials[w * 2 + 1] = vqacc;
  }
}

// ---------------- finalize: reduce per-wave partials, write scalars ----------------
__global__ __launch_bounds__(256) void vq_fin(const float* __restrict__ partials,
                                              float* __restrict__ out) {
  float r = 0.f, v = 0.f;
  for (int i = threadIdx.x; i < NWAVE; i += 256) {
    r += partials[2 * i];
    v += partials[2 * i + 1];
  }
#pragma unroll
  for (int off = 1; off < 64; off <<= 1) {
    r += __shfl_xor(r, off, 64);
    v += __shfl_xor(v, off, 64);
  }
  __shared__ float s[4][2];
  int w = threadIdx.x >> 6;
  if ((threadIdx.x & 63) == 0) { s[w][0] = r; s[w][1] = v; }
  __syncthreads();
  if (threadIdx.x == 0) {
    float R = s[0][0] + s[1][0] + s[2][0] + s[3][0];
    float V = s[0][1] + s[1][1] + s[2][1] + s[3][1];
    out[7340032] = R * (1.0f / 7340032.0f);          // recon_loss = S / (B*28)
    out[7340033] = V * (1.25f / 16777216.0f);        // vq_loss = 1.25 * S / (B*64)
  }
}

extern "C" void kernel_launch(void* const* d_in, const int* in_sizes, int n_in,
                              void* d_out, int out_size, void* d_ws, size_t ws_size,
                              hipStream_t stream) {
  const float* x   = (const float*)d_in[0];
  const float* ew1 = (const float*)d_in[1];
  const float* eb1 = (const float*)d_in[2];
  const float* ew2 = (const float*)d_in[3];
  const float* eb2 = (const float*)d_in[4];
  const float* cb  = (const float*)d_in[5];
  const float* dw1 = (const float*)d_in[6];
  const float* db1 = (const float*)d_in[7];
  const float* dw2 = (const float*)d_in[8];
  const float* db2 = (const float*)d_in[9];

  char* ws = (char*)d_ws;
  unsigned short* blob = (unsigned short*)(ws + 0);   // 131968 B
  float* partials = (float*)(ws + 132096);            // 32768 B (4096*2 f32)

  float* out = (float*)d_out;

  // allow >64 KB dynamic LDS (gfx950 workgroup max is 160 KB)
  (void)hipFuncSetAttribute((const void*)vq_main,
                            hipFuncAttributeMaxDynamicSharedMemorySize, LDS_BYTES);

  vq_prep<<<(PREP_END + 255) / 256, 256, 0, stream>>>(
      ew1, eb1, ew2, eb2, cb, dw1, db1, dw2, db2, blob);
  vq_main<<<NBLK, 1024, LDS_BYTES, stream>>>(x, blob, out, partials);
  vq_fin<<<1, 256, 0, stream>>>(partials, out);
}

// Round 10
// 131.520 us; speedup vs baseline: 1.0790x; 1.0790x over previous
//
#include <hip/hip_runtime.h>

#define BATCH   262144
#define IN_DIM  28
#define HID     128
#define LAT     64
#define NCODES  512
#define NBLK    256             // 1024 rows per block (16 waves x 64 rows)
#define WVS     16
#define NWAVE   (NBLK * WVS)    // 4096

// ---- quad-grouped LDS table geometry ----
// Element (row,k) stored at row*S + q'*(K/4) + j*4 + e where k = j*16 + q'*4 + e.
// A lane (lm, quad) reads K/4 CONTIGUOUS shorts at row*S + quad*(K/4): pure
// ds_read_b128, 16B-aligned. Strides 40/72/136 shorts give 2-way bank aliasing
// only (free). Each v8s read covers TWO logical-k chunks, feeding ONE
// mfma_16x16x32 (k-relabeling valid: both operands share the slot ordering).
#define S1 40     // lw1  [128][40]  K=32  (k>=28 zero)
#define S2 136    // lw2/ld2 [..][136] K=128
#define SC 72     // lcb/ld1 [..][72]  K=64
#define O_LW1 0
#define O_LW2 5120
#define O_LCB 13824
#define O_LD1 50688
#define O_LD2 59904
#define BLOB_SHORTS 64256
#define BLOB_F32    864
#define BLOB_BYTES  (BLOB_SHORTS * 2 + BLOB_F32 * 4)   // 131968
#define LDS_BYTES   BLOB_BYTES

// prep thread-index regions (e2 is 8-lane-parallel)
#define E2_BASE   BLOB_SHORTS            // 4096 threads (8 per code)
#define B1_BASE   (BLOB_SHORTS + 4096)
#define B2_BASE   (B1_BASE + 128)
#define DB1_BASE  (B2_BASE + 64)
#define DB2_BASE  (DB1_BASE + 128)
#define PREP_END  (DB2_BASE + 32)

typedef short v4s __attribute__((ext_vector_type(4)));
typedef short v8s __attribute__((ext_vector_type(8)));
typedef float v4f __attribute__((ext_vector_type(4)));

union u4v8 { unsigned u[4]; v8s s; };

__device__ __forceinline__ unsigned short f2bf(float f) {   // RNE (prep only)
  unsigned u = __float_as_uint(f);
  u += 0x7fffu + ((u >> 16) & 1u);
  return (unsigned short)(u >> 16);
}
// pack two truncated bf16 (hi, lo) in ONE v_perm_b32 (truncation validated r7/r8)
__device__ __forceinline__ unsigned pk(float hi, float lo) {
  return __builtin_amdgcn_perm(__float_as_uint(hi), __float_as_uint(lo), 0x07060302u);
}
// unpack truncated-bf16 lanes of a pk'd u32 back to f32 (for the loss diff)
__device__ __forceinline__ float xf0(unsigned u) { return __uint_as_float(u << 16); }
__device__ __forceinline__ float xf1(unsigned u) { return __uint_as_float(u & 0xFFFF0000u); }

// 16x16x32 bf16 MFMA. C-layout row = quad*4+r (shape-determined, same as x16),
// so chained stages keep working; the v8s B-operand is two pk'd register pairs.
__device__ __forceinline__ v4f mfma32(v8s a, v8s b, v4f c) {
  return __builtin_amdgcn_mfma_f32_16x16x32_bf16(a, b, c, 0, 0, 0);
}

__device__ __forceinline__ v8s rlpk2(v4f h0, v4f h1) {   // relu+pack 2 C-tiles
  u4v8 c;
  c.u[0] = pk(fmaxf(h0[1], 0.f), fmaxf(h0[0], 0.f));
  c.u[1] = pk(fmaxf(h0[3], 0.f), fmaxf(h0[2], 0.f));
  c.u[2] = pk(fmaxf(h1[1], 0.f), fmaxf(h1[0], 0.f));
  c.u[3] = pk(fmaxf(h1[3], 0.f), fmaxf(h1[2], 0.f));
  return c.s;
}
__device__ __forceinline__ v8s zpk2(v4f z0, v4f z1) {    // pack 2 C-tiles
  u4v8 c;
  c.u[0] = pk(z0[1], z0[0]); c.u[1] = pk(z0[3], z0[2]);
  c.u[2] = pk(z1[1], z1[0]); c.u[3] = pk(z1[3], z1[2]);
  return c.s;
}
__device__ __forceinline__ v8s mkv8(unsigned a, unsigned b, unsigned c2, unsigned d) {
  u4v8 c; c.u[0] = a; c.u[1] = b; c.u[2] = c2; c.u[3] = d; return c.s;
}
// argmin key: dist upper bits | 9-bit code (float order == dist order to 2^-14 rel;
// lowest code wins ties among equal upper bits)
__device__ __forceinline__ float kpack(float d, unsigned code) {
  return __uint_as_float((__float_as_uint(d) & 0xFFFFFE00u) | code);
}

// Blob layout (short offsets), quad-grouped, pad zeroed:
//   lw1 @0      [128 hid][40]   enc_w1^T   (K=32 slot, k>=28 zero)
//   lw2 @5120   [64  lat][136]  enc_w2^T   (K=128)
//   lcb @13824  [512 code][72]  bf16(-2*codebook) (K=64)
//   ld1 @50688  [128 hid][72]   bf16(-0.5*dec_w1^T)  (scale cancels -2q)
//   ld2 @59904  [32  n][136]    dec_w2^T   (rows n>=28 zero)
// f32 @ byte 128512: e2[512], b1[128], b2[64], db1[128], db2[32 pad0]
__global__ __launch_bounds__(256) void vq_prep(
    const float* __restrict__ ew1, const float* __restrict__ eb1,
    const float* __restrict__ ew2, const float* __restrict__ eb2,
    const float* __restrict__ cb,  const float* __restrict__ dw1,
    const float* __restrict__ db1, const float* __restrict__ dw2,
    const float* __restrict__ db2,
    unsigned short* __restrict__ blob) {
  int i = blockIdx.x * 256 + threadIdx.x;
  float* fb = (float*)(blob + BLOB_SHORTS);
  if (i < O_LW2) {                       // lw1 [128][40] K=32 per=8
    int row = i / S1, s = i % S1;
    unsigned short v = 0;
    if (s < 32) {
      int q = s >> 3, r2 = s & 7, j = r2 >> 2, e = r2 & 3;
      int k = j * 16 + q * 4 + e;
      if (k < IN_DIM) v = f2bf(ew1[k * HID + row]);
    }
    blob[i] = v;
  } else if (i < O_LCB) {                // lw2 [64][136] K=128 per=32
    int j2 = i - O_LW2; int row = j2 / S2, s = j2 % S2;
    unsigned short v = 0;
    if (s < 128) {
      int q = s >> 5, r2 = s & 31, j = r2 >> 2, e = r2 & 3;
      int k = j * 16 + q * 4 + e;
      v = f2bf(ew2[k * LAT + row]);
    }
    blob[i] = v;
  } else if (i < O_LD1) {                // lcb [512][72] K=64 per=16, = -2*cb
    int j2 = i - O_LCB; int row = j2 / SC, s = j2 % SC;
    unsigned short v = 0;
    if (s < 64) {
      int q = s >> 4, r2 = s & 15, j = r2 >> 2, e = r2 & 3;
      int k = j * 16 + q * 4 + e;
      v = f2bf(-2.0f * cb[row * LAT + k]);
    }
    blob[i] = v;
  } else if (i < O_LD2) {                // ld1 [128][72] = -0.5*dec_w1^T
    int j2 = i - O_LD1; int row = j2 / SC, s = j2 % SC;
    unsigned short v = 0;
    if (s < 64) {
      int q = s >> 4, r2 = s & 15, j = r2 >> 2, e = r2 & 3;
      int k = j * 16 + q * 4 + e;
      v = f2bf(-0.5f * dw1[k * HID + row]);
    }
    blob[i] = v;
  } else if (i < BLOB_SHORTS) {          // ld2 [32][136]
    int j2 = i - O_LD2; int row = j2 / S2, s = j2 % S2;
    unsigned short v = 0;
    if (s < 128 && row < IN_DIM) {
      int q = s >> 5, r2 = s & 31, j = r2 >> 2, e = r2 & 3;
      int k = j * 16 + q * 4 + e;
      v = f2bf(dw2[k * IN_DIM + row]);
    }
    blob[i] = v;
  } else if (i < B1_BASE) {              // e2: 8 lanes per code, float4 loads
    int j = i - E2_BASE;                 // wave-aligned region
    int c = j >> 3, l = j & 7;
    const float* p = cb + c * LAT + l * 8;
    float4 a = *(const float4*)p;
    float4 b = *(const float4*)(p + 4);
    float s = a.x * a.x + a.y * a.y + a.z * a.z + a.w * a.w
            + b.x * b.x + b.y * b.y + b.z * b.z + b.w * b.w;
    s += __shfl_xor(s, 1, 64);
    s += __shfl_xor(s, 2, 64);
    s += __shfl_xor(s, 4, 64);
    if (l == 0) fb[c] = s;
  } else if (i < B2_BASE) {
    fb[512 + (i - B1_BASE)] = eb1[i - B1_BASE];
  } else if (i < DB1_BASE) {
    fb[640 + (i - B2_BASE)] = eb2[i - B2_BASE];
  } else if (i < DB2_BASE) {
    fb[704 + (i - DB1_BASE)] = db1[i - DB1_BASE];
  } else if (i < PREP_END) {
    int k = i - DB2_BASE;
    fb[832 + k] = (k < IN_DIM) ? db2[k] : 0.f;
  }
}

// ---- 2-tile stage 1+2 (mfma32): unchanged from r17 (proven spill-free) ----
__device__ __forceinline__ void s12_pair(
    const unsigned short* __restrict__ L, const float* __restrict__ LF,
    int lm, int quad, v8s bxa, v8s bxb,
    v8s& zfa01, v8s& zfa23, v8s& zfb01, v8s& zfb23,
    float& z2a, float& z2b) {
  const int fw1 = O_LW1 + lm * S1 + quad * 8;
  const int fw2 = O_LW2 + lm * S2 + quad * 32;
  v4f za[4], zb[4];
#pragma unroll
  for (int nt = 0; nt < 4; ++nt) {
    v4f s = *(const v4f*)&LF[640 + nt * 16 + quad * 4];      // b2 seed (broadcast)
    za[nt] = s; zb[nt] = s;
  }
#pragma unroll 1
  for (int jp = 0; jp < 4; ++jp) {
    v8s hA, hB;
    {
      v8s w0 = *(const v8s*)&L[fw1 + (2 * jp) * (16 * S1)];
      v4f s0 = *(const v4f*)&LF[512 + (2 * jp) * 16 + quad * 4];     // b1 seed
      v8s w1 = *(const v8s*)&L[fw1 + (2 * jp + 1) * (16 * S1)];
      v4f s1 = *(const v4f*)&LF[512 + (2 * jp + 1) * 16 + quad * 4];
      v4f h0a = mfma32(w0, bxa, s0);
      v4f h1a = mfma32(w1, bxa, s1);
      v4f h0b = mfma32(w0, bxb, s0);
      v4f h1b = mfma32(w1, bxb, s1);
      hA = rlpk2(h0a, h1a);
      hB = rlpk2(h0b, h1b);
    }
#pragma unroll
    for (int nt = 0; nt < 4; ++nt) {
      v8s w2 = *(const v8s*)&L[fw2 + nt * (16 * S2) + jp * 8];
      za[nt] = mfma32(w2, hA, za[nt]);
      zb[nt] = mfma32(w2, hB, zb[nt]);
    }
  }
  z2a = za[0][0] * za[0][0] + za[0][1] * za[0][1] + za[0][2] * za[0][2] + za[0][3] * za[0][3]
      + za[1][0] * za[1][0] + za[1][1] * za[1][1] + za[1][2] * za[1][2] + za[1][3] * za[1][3]
      + za[2][0] * za[2][0] + za[2][1] * za[2][1] + za[2][2] * za[2][2] + za[2][3] * za[2][3]
      + za[3][0] * za[3][0] + za[3][1] * za[3][1] + za[3][2] * za[3][2] + za[3][3] * za[3][3];
  z2b = zb[0][0] * zb[0][0] + zb[0][1] * zb[0][1] + zb[0][2] * zb[0][2] + zb[0][3] * zb[0][3]
      + zb[1][0] * zb[1][0] + zb[1][1] * zb[1][1] + zb[1][2] * zb[1][2] + zb[1][3] * zb[1][3]
      + zb[2][0] * zb[2][0] + zb[2][1] * zb[2][1] + zb[2][2] * zb[2][2] + zb[2][3] * zb[2][3]
      + zb[3][0] * zb[3][0] + zb[3][1] * zb[3][1] + zb[3][2] * zb[3][2] + zb[3][3] * zb[3][3];
  zfa01 = zpk2(za[0], za[1]); zfa23 = zpk2(za[2], za[3]);
  zfb01 = zpk2(zb[0], zb[1]); zfb23 = zpk2(zb[2], zb[3]);
}

// ---- 2-tile stage 5+6 (mfma32): unchanged from r17 ----
__device__ __forceinline__ void s56_pair(
    const unsigned short* __restrict__ L, const float* __restrict__ LF,
    int lm, int quad, int codeA, int codeB,
    unsigned xa0, unsigned xa1, unsigned xa2, unsigned xa3,
    unsigned xb0, unsigned xb1, unsigned xb2, unsigned xb3,
    float* __restrict__ orowA, float* __restrict__ orowB, float& racc) {
  const int fd1 = O_LD1 + lm * SC + quad * 16;
  const int fd2 = O_LD2 + lm * S2 + quad * 32;
  const int gA = O_LCB + codeA * SC + quad * 16;   // -2q rows (wave-uniform code)
  const int gB = O_LCB + codeB * SC + quad * 16;
  v8s qa0 = *(const v8s*)&L[gA];
  v8s qa1 = *(const v8s*)&L[gA + 8];
  v8s qb0 = *(const v8s*)&L[gB];
  v8s qb1 = *(const v8s*)&L[gB + 8];
  v4f a6a[2], a6b[2];
#pragma unroll
  for (int nt = 0; nt < 2; ++nt) {
    v4f s = *(const v4f*)&LF[832 + nt * 16 + quad * 4];      // db2 seed
    a6a[nt] = s; a6b[nt] = s;
  }
#pragma unroll 1
  for (int jp = 0; jp < 4; ++jp) {
    v8s hA, hB;
    {
      int j0 = 2 * jp;
      v8s d00 = *(const v8s*)&L[fd1 + j0 * (16 * SC)];
      v8s d01 = *(const v8s*)&L[fd1 + j0 * (16 * SC) + 8];
      v4f s0 = *(const v4f*)&LF[704 + j0 * 16 + quad * 4];   // db1 seed
      v8s d10 = *(const v8s*)&L[fd1 + (j0 + 1) * (16 * SC)];
      v8s d11 = *(const v8s*)&L[fd1 + (j0 + 1) * (16 * SC) + 8];
      v4f s1 = *(const v4f*)&LF[704 + (j0 + 1) * 16 + quad * 4];
      v4f h0 = mfma32(d00, qa0, s0);
      h0 = mfma32(d01, qa1, h0);
      v4f h1 = mfma32(d10, qa0, s1);
      h1 = mfma32(d11, qa1, h1);
      hA = rlpk2(h0, h1);
      h0 = mfma32(d00, qb0, s0);
      h0 = mfma32(d01, qb1, h0);
      h1 = mfma32(d10, qb0, s1);
      h1 = mfma32(d11, qb1, h1);
      hB = rlpk2(h0, h1);
    }
#pragma unroll
    for (int nt = 0; nt < 2; ++nt) {
      v8s w6 = *(const v8s*)&L[fd2 + nt * (16 * S2) + jp * 8];
      a6a[nt] = mfma32(w6, hA, a6a[nt]);
      a6b[nt] = mfma32(w6, hB, a6b[nt]);
    }
  }
  *(float4*)(orowA + quad * 4) = (float4){a6a[0][0], a6a[0][1], a6a[0][2], a6a[0][3]};
  *(float4*)(orowB + quad * 4) = (float4){a6b[0][0], a6b[0][1], a6b[0][2], a6b[0][3]};
  if (quad < 3) {
    *(float4*)(orowA + 16 + quad * 4) = (float4){a6a[1][0], a6a[1][1], a6a[1][2], a6a[1][3]};
    *(float4*)(orowB + 16 + quad * 4) = (float4){a6b[1][0], a6b[1][1], a6b[1][2], a6b[1][3]};
  }
  float d;
  d = a6a[0][0] - xf0(xa0); racc += d * d;
  d = a6a[0][1] - xf1(xa0); racc += d * d;
  d = a6a[0][2] - xf0(xa1); racc += d * d;
  d = a6a[0][3] - xf1(xa1); racc += d * d;
  d = a6a[1][0] - xf0(xa2); racc += d * d;   // quad3: a6[1]==0 and x==0
  d = a6a[1][1] - xf1(xa2); racc += d * d;
  d = a6a[1][2] - xf0(xa3); racc += d * d;
  d = a6a[1][3] - xf1(xa3); racc += d * d;
  d = a6b[0][0] - xf0(xb0); racc += d * d;
  d = a6b[0][1] - xf1(xb0); racc += d * d;
  d = a6b[0][2] - xf0(xb1); racc += d * d;
  d = a6b[0][3] - xf1(xb1); racc += d * d;
  d = a6b[1][0] - xf0(xb2); racc += d * d;
  d = a6b[1][1] - xf1(xb2); racc += d * d;
  d = a6b[1][2] - xf0(xb3); racc += d * d;
  d = a6b[1][3] - xf1(xb3); racc += d * d;
}

// ---------------- fused main kernel ----------------
// Round-19: r18's 4-tile argmin spilled (FETCH 37/WRITE 99 MB) -- the arch-VGPR
// cap here is a hard 64, closing the "share more tiles" direction. REVERT to
// r17 (proven 43us main / 131.9 total) with ONE zero-register-footprint change:
// the three inter-phase sched_barrier(0) calls are REMOVED. They were added in
// r13 alongside the unroll-1 jp-loops; the unroll-1 back-edges are the actual
// spill guard (cap ~6 v8s in flight), while the barriers provably forbid
// cross-phase overlap: next-sweep x-loads under S56, argmin cb reads under
// S12's tail, q-gather under the argmin reduce. FETCH/WRITE are the spill
// tripwire; fallback is r17 verbatim.
__global__ __attribute__((amdgpu_flat_work_group_size(1024, 1024)))
__attribute__((amdgpu_waves_per_eu(4, 4)))
void vq_main(
    const float* __restrict__ x,
    const unsigned short* __restrict__ blob,
    float* __restrict__ out, float* __restrict__ partials) {

  extern __shared__ __align__(16) char smem[];
  const unsigned short* L = (const unsigned short*)smem;
  const float*         LF = (const float*)(smem + BLOB_SHORTS * 2);

  const int tid  = threadIdx.x;
  const int wave = tid >> 6;
  const int lane = tid & 63;
  const int quad = lane >> 4;
  const int lm   = lane & 15;

  // ---- stage tables into LDS (one-time) ----
  {
    const float4* src = (const float4*)blob;
    float4* dst = (float4*)smem;
#pragma unroll
    for (int it = 0; it < 9; ++it) {
      int idx = it * 1024 + tid;
      if (idx < BLOB_BYTES / 16) dst[idx] = src[idx];
    }
  }
  __syncthreads();

  const int rbase = blockIdx.x * 1024 + wave * 64;
  float racc = 0.f, vqacc = 0.f;

#pragma unroll 1
  for (int sw = 0; sw < 2; ++sw) {
    const int r0 = rbase + sw * 32;

    // ---- x load -> packed bf16 only (f32 temps die immediately) ----
    unsigned xa0, xa1, xa2, xa3, xb0, xb1, xb2, xb3;
    {
      const float* xpa = x + (size_t)(r0 + lm) * IN_DIM;
      const float* xpb = x + (size_t)(r0 + 16 + lm) * IN_DIM;
      float4 t = *(const float4*)(xpa + quad * 4);
      xa0 = pk(t.y, t.x); xa1 = pk(t.w, t.z);
      t = (quad < 3) ? *(const float4*)(xpa + 16 + quad * 4) : (float4){0.f, 0.f, 0.f, 0.f};
      xa2 = pk(t.y, t.x); xa3 = pk(t.w, t.z);
      t = *(const float4*)(xpb + quad * 4);
      xb0 = pk(t.y, t.x); xb1 = pk(t.w, t.z);
      t = (quad < 3) ? *(const float4*)(xpb + 16 + quad * 4) : (float4){0.f, 0.f, 0.f, 0.f};
      xb2 = pk(t.y, t.x); xb3 = pk(t.w, t.z);
    }

    // ---- stages 1+2, tiles A+B together (fragments shared, mfma32) ----
    v8s zfa01, zfa23, zfb01, zfb23;
    float z2a, z2b;
    s12_pair(L, LF, lm, quad,
             mkv8(xa0, xa1, xa2, xa3), mkv8(xb0, xb1, xb2, xb3),
             zfa01, zfa23, zfb01, zfb23, z2a, z2b);

    // ---- argmin: dist^T = e2 + (-2e)·z; cb fragments SHARED by both tiles ----
    const int fcb = O_LCB + lm * SC + quad * 16;
    float bkA = __uint_as_float(0x7f7fffffu);
    float bkB = bkA;
#pragma unroll 2
    for (int ct = 0; ct < 32; ++ct) {
      v8s c0 = *(const v8s*)&L[fcb + ct * (16 * SC)];        // k-chunks 0,1
      v8s c1 = *(const v8s*)&L[fcb + ct * (16 * SC) + 8];    // k-chunks 2,3
      v4f sd = *(const v4f*)&LF[ct * 16 + quad * 4];         // e2 seed
      v4f dA = mfma32(c0, zfa01, sd);
      dA = mfma32(c1, zfa23, dA);
      v4f dB = mfma32(c0, zfb01, sd);
      dB = mfma32(c1, zfb23, dB);
      unsigned cbase = (unsigned)(ct * 16 + quad * 4);
      bkA = fminf(bkA, fminf(fminf(kpack(dA[0], cbase), kpack(dA[1], cbase + 1)),
                             fminf(kpack(dA[2], cbase + 2), kpack(dA[3], cbase + 3))));
      bkB = fminf(bkB, fminf(fminf(kpack(dB[0], cbase), kpack(dB[1], cbase + 1)),
                             fminf(kpack(dB[2], cbase + 2), kpack(dB[3], cbase + 3))));
    }

    // ---- cross-quad argmin + z2 reduce ----
#pragma unroll
    for (int off = 16; off < 64; off <<= 1) {
      bkA = fminf(bkA, __shfl_xor(bkA, off, 64));
      bkB = fminf(bkB, __shfl_xor(bkB, off, 64));
      z2a += __shfl_xor(z2a, off, 64);
      z2b += __shfl_xor(z2b, off, 64);
    }
    unsigned ka = __float_as_uint(bkA), kb = __float_as_uint(bkB);
    int codeA = (int)(ka & 511u), codeB = (int)(kb & 511u);
    if (quad == 0)
      vqacc += z2a + __uint_as_float(ka & 0xFFFFFE00u)
             + z2b + __uint_as_float(kb & 0xFFFFFE00u);      // ||z-q||^2

    // ---- stages 5+6 + store + loss, tiles A+B together (mfma32) ----
    s56_pair(L, LF, lm, quad, codeA, codeB,
             xa0, xa1, xa2, xa3, xb0, xb1, xb2, xb3,
             out + (size_t)(r0 + lm) * IN_DIM,
             out + (size_t)(r0 + 16 + lm) * IN_DIM, racc);
  }

  // ---- per-wave butterfly, per-wave partial store (no atomics) ----
#pragma unroll
  for (int off = 1; off < 64; off <<= 1) {
    racc  += __shfl_xor(racc, off, 64);
    vqacc += __shfl_xor(vqacc, off, 64);
  }
  if (lane == 0) {
    size_t w = (size_t)blockIdx.x * WVS + wave;
    partials[w * 2]     = racc;
    partials[w * 2 + 1] = vqacc;
  }
}

// ---------------- finalize: reduce per-wave partials, write scalars ----------------
__global__ __launch_bounds__(256) void vq_fin(const float* __restrict__ partials,
                                              float* __restrict__ out) {
  float r = 0.f, v = 0.f;
  for (int i = threadIdx.x; i < NWAVE; i += 256) {
    r += partials[2 * i];
    v += partials[2 * i + 1];
  }
#pragma unroll
  for (int off = 1; off < 64; off <<= 1) {
    r += __shfl_xor(r, off, 64);
    v += __shfl_xor(v, off, 64);
  }
  __shared__ float s[4][2];
  int w = threadIdx.x >> 6;
  if ((threadIdx.x & 63) == 0) { s[w][0] = r; s[w][1] = v; }
  __syncthreads();
  if (threadIdx.x == 0) {
    float R = s[0][0] + s[1][0] + s[2][0] + s[3][0];
    float V = s[0][1] + s[1][1] + s[2][1] + s[3][1];
    out[7340032] = R * (1.0f / 7340032.0f);          // recon_loss = S / (B*28)
    out[7340033] = V * (1.25f / 16777216.0f);        // vq_loss = 1.25 * S / (B*64)
  }
}

extern "C" void kernel_launch(void* const* d_in, const int* in_sizes, int n_in,
                              void* d_out, int out_size, void* d_ws, size_t ws_size,
                              hipStream_t stream) {
  const float* x   = (const float*)d_in[0];
  const float* ew1 = (const float*)d_in[1];
  const float* eb1 = (const float*)d_in[2];
  const float* ew2 = (const float*)d_in[3];
  const float* eb2 = (const float*)d_in[4];
  const float* cb  = (const float*)d_in[5];
  const float* dw1 = (const float*)d_in[6];
  const float* db1 = (const float*)d_in[7];
  const float* dw2 = (const float*)d_in[8];
  const float* db2 = (const float*)d_in[9];

  char* ws = (char*)d_ws;
  unsigned short* blob = (unsigned short*)(ws + 0);   // 131968 B
  float* partials = (float*)(ws + 132096);            // 32768 B (4096*2 f32)

  float* out = (float*)d_out;

  // allow >64 KB dynamic LDS (gfx950 workgroup max is 160 KB)
  (void)hipFuncSetAttribute((const void*)vq_main,
                            hipFuncAttributeMaxDynamicSharedMemorySize, LDS_BYTES);

  vq_prep<<<(PREP_END + 255) / 256, 256, 0, stream>>>(
      ew1, eb1, ew2, eb2, cb, dw1, db1, dw2, db2, blob);
  vq_main<<<NBLK, 1024, LDS_BYTES, stream>>>(x, blob, out, partials);
  vq_fin<<<1, 256, 0, stream>>>(partials, out);
}